// Round 2
// baseline (455.660 us; speedup 1.0000x reference)
//
#include <hip/hip_runtime.h>
#include <math.h>

#define TT 2048   // tokens
#define HH 1024   // hidden
#define EE 8      // experts
#define II 2048   // intermediate
#define N1 4096   // 2*II
#define ALPHA 1.702f
#define LIMIT 7.0f
#define MAXSCHED 40
#define SPLITK 2

typedef __attribute__((ext_vector_type(8))) short short8;
typedef __attribute__((ext_vector_type(4))) float floatx4;

#define GLL(g, l) __builtin_amdgcn_global_load_lds(                          \
    (const __attribute__((address_space(1))) void*)(g),                      \
    (__attribute__((address_space(3))) void*)(l), 16, 0, 0)

__device__ __forceinline__ short f2bf(float f) {
  union { float f; unsigned u; } v; v.f = f;
  unsigned r = (v.u + 0x7fffu + ((v.u >> 16) & 1u)) >> 16;
  return (short)r;
}
__device__ __forceinline__ float bf2f(unsigned short s) {
  union { unsigned u; float f; } v; v.u = ((unsigned)s) << 16;
  return v.f;
}

// ---------------- x f32 -> bf16 ----------------
__global__ __launch_bounds__(256) void convert_x(const float* __restrict__ x,
                                                 unsigned short* __restrict__ xb) {
  const size_t off = ((size_t)blockIdx.x * blockDim.x + threadIdx.x) * 8;
  const float4 v0 = *(const float4*)(x + off);
  const float4 v1 = *(const float4*)(x + off + 4);
  short8 s;
  s[0]=f2bf(v0.x); s[1]=f2bf(v0.y); s[2]=f2bf(v0.z); s[3]=f2bf(v0.w);
  s[4]=f2bf(v1.x); s[5]=f2bf(v1.y); s[6]=f2bf(v1.z); s[7]=f2bf(v1.w);
  *(short8*)(xb + off) = s;
}

// ------------- weight transpose+convert: src [E][K][N] f32 -> dst [E][N][K] bf16
__global__ __launch_bounds__(256) void transpose_cvt(const float* __restrict__ src,
                                                     unsigned short* __restrict__ dst,
                                                     int K, int N) {
  const int e = blockIdx.z;
  src += (size_t)e * K * N;
  dst += (size_t)e * K * N;
  const int k0 = blockIdx.y * 64, n0 = blockIdx.x * 64;
  __shared__ unsigned short Ts[64][66];
  const int tid = threadIdx.x;
  const int c4 = (tid & 15) * 4;
  const int r = tid >> 4;
#pragma unroll
  for (int i = 0; i < 4; i++) {
    const int kk = r + i * 16;
    const float4 v = *(const float4*)(src + (size_t)(k0 + kk) * N + n0 + c4);
    Ts[kk][c4 + 0] = (unsigned short)f2bf(v.x);
    Ts[kk][c4 + 1] = (unsigned short)f2bf(v.y);
    Ts[kk][c4 + 2] = (unsigned short)f2bf(v.z);
    Ts[kk][c4 + 3] = (unsigned short)f2bf(v.w);
  }
  __syncthreads();
#pragma unroll
  for (int i = 0; i < 4; i++) {
    const int nn = r + i * 16;
    unsigned short o[4];
#pragma unroll
    for (int j = 0; j < 4; j++) o[j] = Ts[c4 + j][nn];
    *(uint2*)(dst + (size_t)(n0 + nn) * K + k0 + c4) = *(const uint2*)o;
  }
}

// ---------------- router: logits -> softmax -> top2 ----------------
__global__ __launch_bounds__(256) void router_kernel(
    const float* __restrict__ x, const float* __restrict__ rw,
    const float* __restrict__ rb, int* __restrict__ topk_idx,
    float* __restrict__ topk_w) {
  const int t = blockIdx.x;
  const float* xr = x + (size_t)t * HH;
  const int lane = threadIdx.x & 63;
  const int wave = threadIdx.x >> 6;
  float xv[16];
#pragma unroll
  for (int i = 0; i < 16; i++) xv[i] = xr[lane + i * 64];
  __shared__ float logits[EE];
#pragma unroll
  for (int ee = 0; ee < 2; ee++) {
    const int e = wave * 2 + ee;
    const float* wr = rw + (size_t)e * HH;
    float s = 0.f;
#pragma unroll
    for (int i = 0; i < 16; i++) s += xv[i] * wr[lane + i * 64];
#pragma unroll
    for (int off = 32; off > 0; off >>= 1) s += __shfl_down(s, off, 64);
    if (lane == 0) logits[e] = s + rb[e];
  }
  __syncthreads();
  if (threadIdx.x == 0) {
    float sc[EE];
    float mx = -3.4e38f;
    for (int i = 0; i < EE; i++) mx = fmaxf(mx, logits[i]);
    float sum = 0.f;
    for (int i = 0; i < EE; i++) { sc[i] = expf(logits[i] - mx); sum += sc[i]; }
    const float inv = 1.f / sum;
    int i0 = 0;
    for (int i = 1; i < EE; i++) if (sc[i] > sc[i0]) i0 = i;
    int i1 = (i0 == 0) ? 1 : 0;
    for (int i = 0; i < EE; i++) if (i != i0 && sc[i] > sc[i1]) i1 = i;
    topk_idx[t * 2 + 0] = i0;
    topk_idx[t * 2 + 1] = i1;
    topk_w[t * 2 + 0] = sc[i0] * inv;
    topk_w[t * 2 + 1] = sc[i1] * inv;
  }
}

// ---------------- token->expert compaction + schedule ----------------
__global__ void assign_kernel(const int* __restrict__ topk_idx,
                              int* __restrict__ counts, int* __restrict__ rows) {
  const int id = blockIdx.x * blockDim.x + threadIdx.x;
  if (id >= TT * 2) return;
  const int e = topk_idx[id];
  const int slot = atomicAdd(&counts[e], 1);
  rows[e * TT + slot] = id;  // entry = t*2 + k
}

__global__ void sched_kernel(const int* __restrict__ counts,
                             int* __restrict__ sched, int* __restrict__ nsched) {
  if (threadIdx.x == 0) {
    int n = 0;
    for (int e = 0; e < EE; e++) {
      const int mt = (counts[e] + 127) >> 7;
      for (int m = 0; m < mt; m++) sched[n++] = (e << 8) | m;
    }
    nsched[0] = n;
  }
}

// ---------------- GEMM1: x_bf gathered x gup_t[e] -> gu (bf16) ----------------
__global__ __launch_bounds__(256) void gemm_gu(
    const unsigned short* __restrict__ x_bf,
    const unsigned short* __restrict__ gup_t,
    const float* __restrict__ gub,
    const int* __restrict__ counts, const int* __restrict__ rows,
    const int* __restrict__ sched, const int* __restrict__ nsched,
    unsigned short* __restrict__ gu) {
  const int sid = blockIdx.y;
  if (sid >= nsched[0]) return;
  const int sv = sched[sid];
  const int e = sv >> 8, mtile = sv & 255;
  const int count = counts[e] - mtile * 128;  // local live rows (>=1)
  const int ntile = blockIdx.x;
  const int* rl = rows + e * TT + mtile * 128;

  __shared__ short As[128 * 32];
  __shared__ short Bs[128 * 32];

  const int tid = threadIdx.x;
  const int lane = tid & 63, wave = tid >> 6;
  const int quad = lane >> 4, r16 = lane & 15;
  const int wm = (wave & 1) << 6, wn = (wave >> 1) << 6;

  // staging: lane covers LDS row (wave*32 + lane/4 [+16]), 16B k-octet slot lane&3
  // XOR swizzle: slot s of row r holds global octet s^(r&3)
  const int srow = lane >> 2;
  const int soct = (lane & 3) ^ (srow & 3);
  const int lr0 = wave * 32 + srow;
  const int lr1 = lr0 + 16;
  const int cr0 = (lr0 < count) ? lr0 : 0;
  const int cr1 = (lr1 < count) ? lr1 : 0;
  const unsigned short* aptr0 = x_bf + (size_t)(rl[cr0] >> 1) * HH + soct * 8;
  const unsigned short* aptr1 = x_bf + (size_t)(rl[cr1] >> 1) * HH + soct * 8;
  const unsigned short* bptr0 = gup_t + (size_t)e * N1 * HH +
                                (size_t)(ntile * 128 + lr0) * HH + soct * 8;
  const unsigned short* bptr1 = bptr0 + (size_t)16 * HH;

  short* lA0 = As + (wave * 32) * 32;
  short* lA1 = As + (wave * 32 + 16) * 32;
  short* lB0 = Bs + (wave * 32) * 32;
  short* lB1 = Bs + (wave * 32 + 16) * 32;

  const int fcol = (quad ^ (r16 & 3)) * 8;
  const short8* ap[4]; const short8* bp[4];
#pragma unroll
  for (int i = 0; i < 4; i++) {
    ap[i] = (const short8*)&As[(wm + i * 16 + r16) * 32 + fcol];
    bp[i] = (const short8*)&Bs[(wn + i * 16 + r16) * 32 + fcol];
  }

  floatx4 acc[4][4] = {};
  for (int k0 = 0; k0 < HH; k0 += 32) {
    __syncthreads();
    GLL(aptr0 + k0, lA0);
    GLL(aptr1 + k0, lA1);
    GLL(bptr0 + k0, lB0);
    GLL(bptr1 + k0, lB1);
    __syncthreads();
    short8 af[4], bf_[4];
#pragma unroll
    for (int i = 0; i < 4; i++) { af[i] = *ap[i]; bf_[i] = *bp[i]; }
#pragma unroll
    for (int i = 0; i < 4; i++)
#pragma unroll
      for (int j = 0; j < 4; j++)
        acc[i][j] = __builtin_amdgcn_mfma_f32_16x16x32_bf16(af[i], bf_[j], acc[i][j], 0, 0, 0);
  }

  const float* bias = gub + (size_t)e * N1 + ntile * 128;
#pragma unroll
  for (int i = 0; i < 4; i++) {
#pragma unroll
    for (int reg = 0; reg < 4; reg++) {
      const int rrow = wm + i * 16 + quad * 4 + reg;
      if (rrow < count) {
        const int ent = rl[rrow];
        unsigned short* orow = gu + (size_t)ent * N1 + ntile * 128;
#pragma unroll
        for (int j = 0; j < 4; j++) {
          const int c = wn + j * 16 + r16;
          orow[c] = (unsigned short)f2bf(acc[i][j][reg] + bias[c]);
        }
      }
    }
  }
}

// ---------------- activation: gu -> act (bf16) ----------------
__global__ __launch_bounds__(256) void act_kernel(const unsigned short* __restrict__ gu,
                                                  unsigned short* __restrict__ act) {
  const int id = blockIdx.x * blockDim.x + threadIdx.x;  // one per 8 elems
  const int r = id >> 8;                 // II/8 = 256 groups per row
  const int i8 = (id & 255) * 8;
  const short8 g8 = *(const short8*)(gu + (size_t)r * N1 + i8);
  const short8 u8 = *(const short8*)(gu + (size_t)r * N1 + II + i8);
  short8 o;
#pragma unroll
  for (int j = 0; j < 8; j++) {
    float g = bf2f((unsigned short)g8[j]);
    float u = bf2f((unsigned short)u8[j]);
    g = fminf(g, LIMIT);
    u = fminf(fmaxf(u, -LIMIT), LIMIT);
    const float glu = g / (1.f + expf(-g * ALPHA));
    o[j] = f2bf((u + 1.f) * glu);
  }
  *(short8*)(act + (size_t)r * II + i8) = o;
}

// ---------------- GEMM2: act gathered x dp_t[e] -> dout (f32, split-K atomic) --
__global__ __launch_bounds__(256) void gemm_down(
    const unsigned short* __restrict__ act,
    const unsigned short* __restrict__ dp_t,
    const int* __restrict__ counts, const int* __restrict__ rows,
    const int* __restrict__ sched, const int* __restrict__ nsched,
    float* __restrict__ dout) {
  const int sid = blockIdx.y;
  if (sid >= nsched[0]) return;
  const int sv = sched[sid];
  const int e = sv >> 8, mtile = sv & 255;
  const int count = counts[e] - mtile * 128;
  const int ntile = blockIdx.x;
  const int kbase = blockIdx.z * (II / SPLITK);
  const int* rl = rows + e * TT + mtile * 128;

  __shared__ short As[128 * 32];
  __shared__ short Bs[128 * 32];

  const int tid = threadIdx.x;
  const int lane = tid & 63, wave = tid >> 6;
  const int quad = lane >> 4, r16 = lane & 15;
  const int wm = (wave & 1) << 6, wn = (wave >> 1) << 6;

  const int srow = lane >> 2;
  const int soct = (lane & 3) ^ (srow & 3);
  const int lr0 = wave * 32 + srow;
  const int lr1 = lr0 + 16;
  const int cr0 = (lr0 < count) ? lr0 : 0;
  const int cr1 = (lr1 < count) ? lr1 : 0;
  const unsigned short* aptr0 = act + (size_t)rl[cr0] * II + soct * 8;
  const unsigned short* aptr1 = act + (size_t)rl[cr1] * II + soct * 8;
  const unsigned short* bptr0 = dp_t + (size_t)e * HH * II +
                                (size_t)(ntile * 128 + lr0) * II + soct * 8;
  const unsigned short* bptr1 = bptr0 + (size_t)16 * II;

  short* lA0 = As + (wave * 32) * 32;
  short* lA1 = As + (wave * 32 + 16) * 32;
  short* lB0 = Bs + (wave * 32) * 32;
  short* lB1 = Bs + (wave * 32 + 16) * 32;

  const int fcol = (quad ^ (r16 & 3)) * 8;
  const short8* ap[4]; const short8* bp[4];
#pragma unroll
  for (int i = 0; i < 4; i++) {
    ap[i] = (const short8*)&As[(wm + i * 16 + r16) * 32 + fcol];
    bp[i] = (const short8*)&Bs[(wn + i * 16 + r16) * 32 + fcol];
  }

  floatx4 acc[4][4] = {};
  for (int k0 = kbase; k0 < kbase + II / SPLITK; k0 += 32) {
    __syncthreads();
    GLL(aptr0 + k0, lA0);
    GLL(aptr1 + k0, lA1);
    GLL(bptr0 + k0, lB0);
    GLL(bptr1 + k0, lB1);
    __syncthreads();
    short8 af[4], bf_[4];
#pragma unroll
    for (int i = 0; i < 4; i++) { af[i] = *ap[i]; bf_[i] = *bp[i]; }
#pragma unroll
    for (int i = 0; i < 4; i++)
#pragma unroll
      for (int j = 0; j < 4; j++)
        acc[i][j] = __builtin_amdgcn_mfma_f32_16x16x32_bf16(af[i], bf_[j], acc[i][j], 0, 0, 0);
  }

#pragma unroll
  for (int i = 0; i < 4; i++) {
#pragma unroll
    for (int reg = 0; reg < 4; reg++) {
      const int rrow = wm + i * 16 + quad * 4 + reg;
      if (rrow < count) {
        const int ent = rl[rrow];
        float* orow = dout + (size_t)ent * HH + ntile * 128;
#pragma unroll
        for (int j = 0; j < 4; j++) {
          const int c = wn + j * 16 + r16;
          atomicAdd(&orow[c], acc[i][j][reg]);
        }
      }
    }
  }
}

// ---------------- combine: out = w0*(d0+db[e0]) + w1*(d1+db[e1]) ----------------
__global__ __launch_bounds__(256) void combine_kernel(
    const float* __restrict__ dout, const float* __restrict__ tw,
    const int* __restrict__ tidx, const float* __restrict__ db,
    float* __restrict__ out) {
  const int id = blockIdx.x * blockDim.x + threadIdx.x;
  const int t = id >> 8;
  const int h = (id & 255) * 4;
  const float w0 = tw[t * 2], w1 = tw[t * 2 + 1];
  const int e0 = tidx[t * 2], e1 = tidx[t * 2 + 1];
  const float4 a = *(const float4*)(dout + (size_t)(2 * t) * HH + h);
  const float4 b = *(const float4*)(dout + (size_t)(2 * t + 1) * HH + h);
  const float4 b0 = *(const float4*)(db + (size_t)e0 * HH + h);
  const float4 b1 = *(const float4*)(db + (size_t)e1 * HH + h);
  float4 o;
  o.x = w0 * (a.x + b0.x) + w1 * (b.x + b1.x);
  o.y = w0 * (a.y + b0.y) + w1 * (b.y + b1.y);
  o.z = w0 * (a.z + b0.z) + w1 * (b.z + b1.z);
  o.w = w0 * (a.w + b0.w) + w1 * (b.w + b1.w);
  *(float4*)(out + (size_t)t * HH + h) = o;
}

extern "C" void kernel_launch(void* const* d_in, const int* in_sizes, int n_in,
                              void* d_out, int out_size, void* d_ws, size_t ws_size,
                              hipStream_t stream) {
  const float* x   = (const float*)d_in[0];
  const float* rw  = (const float*)d_in[1];
  const float* rb  = (const float*)d_in[2];
  const float* gup = (const float*)d_in[3];
  const float* gub = (const float*)d_in[4];
  const float* dp  = (const float*)d_in[5];
  const float* db  = (const float*)d_in[6];
  float* out = (float*)d_out;

  char* ws = (char*)d_ws;
  // meta
  int*   topk_idx = (int*)(ws + 0);            // 16 KB
  float* topk_w   = (float*)(ws + 16384);      // 16 KB
  int*   counts   = (int*)(ws + 32768);        // 256 B
  int*   nsched   = (int*)(ws + 33024);        // 256 B
  int*   sched    = (int*)(ws + 33280);        // 256 B
  int*   rows     = (int*)(ws + 36864);        // 64 KB
  // big buffers (with lifetime-based aliasing):
  unsigned short* x_bf  = (unsigned short*)(ws + (1u << 20));        // 4 MB
  unsigned short* gup_t = (unsigned short*)(ws + 8388608);           // 64 MB
  unsigned short* act   = (unsigned short*)(ws + 8388608);           // aliases gup_t (dead after gemm_gu)
  unsigned short* dp_t  = (unsigned short*)(ws + 75497472);          // 32 MB
  unsigned short* gu    = (unsigned short*)(ws + 109051904);         // 33.5 MB
  float*          dout  = (float*)(ws + 109051904);                  // aliases gu (dead after act)
  // total footprint: 109051904 + 33554432 = ~136 MB

  convert_x<<<TT * HH / (256 * 8), 256, 0, stream>>>(x, x_bf);
  transpose_cvt<<<dim3(N1 / 64, HH / 64, EE), 256, 0, stream>>>(gup, gup_t, HH, N1);
  transpose_cvt<<<dim3(HH / 64, II / 64, EE), 256, 0, stream>>>(dp, dp_t, II, HH);
  router_kernel<<<TT, 256, 0, stream>>>(x, rw, rb, topk_idx, topk_w);
  hipMemsetAsync(counts, 0, 64, stream);
  assign_kernel<<<(TT * 2 + 255) / 256, 256, 0, stream>>>(topk_idx, counts, rows);
  sched_kernel<<<1, 64, 0, stream>>>(counts, sched, nsched);
  gemm_gu<<<dim3(N1 / 128, MAXSCHED), 256, 0, stream>>>(
      x_bf, gup_t, gub, counts, rows, sched, nsched, gu);
  act_kernel<<<TT * 2 * II / (256 * 8), 256, 0, stream>>>(gu, act);
  hipMemsetAsync(dout, 0, (size_t)TT * 2 * HH * 4, stream);
  gemm_down<<<dim3(HH / 128, MAXSCHED, SPLITK), 256, 0, stream>>>(
      act, dp_t, counts, rows, sched, nsched, dout);
  combine_kernel<<<(TT * HH / 4) / 256, 256, 0, stream>>>(dout, topk_w, topk_idx, db, out);
}